// Round 1
// baseline (8287.971 us; speedup 1.0000x reference)
//
#include <hip/hip_runtime.h>
#include <math.h>

#define N_NODES 100000
#define N_EDGES 3200000
#define F_NODE 4
#define F_EDGE 4
#define LD 6
#define HID 16
#define NLAYER 8
#define D_IN 24   // 2*LD + 2*F_NODE + F_EDGE
#define EPSF 1e-6f
#define XS 8      // padded node-state stride (float4-friendly)

// ---------------- degree ----------------
__global__ __launch_bounds__(256) void deg_kernel(const int* __restrict__ ei,
                                                  float* __restrict__ deg) {
    int e = blockIdx.x * 256 + threadIdx.x;
    if (e < N_EDGES) atomicAdd(&deg[ei[N_EDGES + e]], 1.0f);
}

// ---------------- per-edge MLP + scatter ----------------
__global__ __launch_bounds__(256) void edge_mlp(const int* __restrict__ ei,
                                                const float* __restrict__ x,
                                                const float* __restrict__ ea,
                                                const float* __restrict__ X,
                                                const float* __restrict__ W1,
                                                const float* __restrict__ b1,
                                                const float* __restrict__ W2,
                                                const float* __restrict__ b2,
                                                float* __restrict__ agg) {
    __shared__ float sW1[D_IN * HID];
    __shared__ float sb1[HID];
    __shared__ float sW2[HID * LD];
    __shared__ float sb2[LD];
    for (int i = threadIdx.x; i < D_IN * HID; i += 256) sW1[i] = W1[i];
    for (int i = threadIdx.x; i < HID * LD; i += 256) sW2[i] = W2[i];
    if (threadIdx.x < HID) sb1[threadIdx.x] = b1[threadIdx.x];
    if (threadIdx.x < LD)  sb2[threadIdx.x] = b2[threadIdx.x];
    __syncthreads();

    int e = blockIdx.x * 256 + threadIdx.x;
    if (e >= N_EDGES) return;
    int s = ei[e];
    int d = ei[N_EDGES + e];

    float m[D_IN];
    {   // X[src] (6), X[dst] (6) — padded stride 8, float4 loads
        const float4* Xs = reinterpret_cast<const float4*>(X + (size_t)s * XS);
        const float4* Xd = reinterpret_cast<const float4*>(X + (size_t)d * XS);
        float4 a0 = Xs[0], a1 = Xs[1];
        float4 c0 = Xd[0], c1 = Xd[1];
        m[0] = a0.x; m[1] = a0.y; m[2] = a0.z; m[3] = a0.w; m[4] = a1.x; m[5] = a1.y;
        m[6] = c0.x; m[7] = c0.y; m[8] = c0.z; m[9] = c0.w; m[10] = c1.x; m[11] = c1.y;
        float4 ns = reinterpret_cast<const float4*>(x)[s];
        float4 nd = reinterpret_cast<const float4*>(x)[d];
        m[12] = ns.x; m[13] = ns.y; m[14] = ns.z; m[15] = ns.w;
        m[16] = nd.x; m[17] = nd.y; m[18] = nd.z; m[19] = nd.w;
        float4 ev = reinterpret_cast<const float4*>(ea)[e];
        m[20] = ev.x; m[21] = ev.y; m[22] = ev.z; m[23] = ev.w;
    }

    float h[HID];
#pragma unroll
    for (int j = 0; j < HID; j++) h[j] = sb1[j];
#pragma unroll
    for (int i = 0; i < D_IN; i++) {
        float mi = m[i];
#pragma unroll
        for (int j = 0; j < HID; j++) h[j] = fmaf(mi, sW1[i * HID + j], h[j]);
    }
#pragma unroll
    for (int j = 0; j < HID; j++) h[j] = fmaxf(h[j], 0.0f);

    float out[LD];
#pragma unroll
    for (int o = 0; o < LD; o++) out[o] = sb2[o];
#pragma unroll
    for (int j = 0; j < HID; j++) {
        float hj = h[j];
#pragma unroll
        for (int o = 0; o < LD; o++) out[o] = fmaf(hj, sW2[j * LD + o], out[o]);
    }

    float* aggd = agg + (size_t)d * XS;
#pragma unroll
    for (int o = 0; o < LD; o++) atomicAdd(&aggd[o], out[o]);
}

// ---------------- node update: X = relu(agg / max(deg,1)) ----------------
__global__ __launch_bounds__(256) void node_update(const float* __restrict__ agg,
                                                   const float* __restrict__ deg,
                                                   float* __restrict__ X) {
    int i = blockIdx.x * 256 + threadIdx.x;
    if (i >= N_NODES) return;
    float inv = 1.0f / fmaxf(deg[i], 1.0f);
#pragma unroll
    for (int o = 0; o < LD; o++)
        X[(size_t)i * XS + o] = fmaxf(agg[(size_t)i * XS + o] * inv, 0.0f);
}

// ---------------- head: P = relu(X@Wf + bf); P_ = fixed!=0 ? fixed : P ----------------
__global__ __launch_bounds__(256) void pfinal(const float* __restrict__ X,
                                              const float* __restrict__ x,
                                              const float* __restrict__ Wf,
                                              const float* __restrict__ bf,
                                              float* __restrict__ Pout,
                                              float* __restrict__ Pbuf) {
    int i = blockIdx.x * 256 + threadIdx.x;
    if (i >= N_NODES) return;
    float acc = bf[0];
#pragma unroll
    for (int o = 0; o < LD; o++) acc = fmaf(X[(size_t)i * XS + o], Wf[o], acc);
    float P = fmaxf(acc, 0.0f);
    Pout[i] = P;
    float fixed = x[i * F_NODE + 3];
    Pbuf[i] = (fixed != 0.0f) ? fixed : P;
}

// ---------------- flows + balance scatter ----------------
__global__ __launch_bounds__(256) void flows_kernel(const int* __restrict__ ei,
                                                    const float* __restrict__ ea,
                                                    const float* __restrict__ Pbuf,
                                                    float* __restrict__ flows_out,
                                                    float* __restrict__ bal) {
    int e = blockIdx.x * 256 + threadIdx.x;
    if (e >= N_EDGES) return;
    int s = ei[e];
    int d = ei[N_EDGES + e];
    float ps = Pbuf[s], pd = Pbuf[d];
    float dp2 = ps * ps - pd * pd;
    float k = ea[(size_t)e * F_EDGE];
    float sg = (dp2 > 0.0f) ? 1.0f : ((dp2 < 0.0f) ? -1.0f : 0.0f);
    float f = sg * sqrtf(fabsf(dp2) / k + EPSF);
    flows_out[e] = f;
    atomicAdd(&bal[d], f);
    atomicAdd(&bal[s], -f);
}

// ---------------- imbalance = sqrt(sum((bal+inj)^2)) ----------------
__global__ __launch_bounds__(256) void imb_kernel(const float* __restrict__ bal,
                                                  const float* __restrict__ x,
                                                  float* __restrict__ imb2) {
    int i = blockIdx.x * 256 + threadIdx.x;
    float v = 0.0f;
    if (i < N_NODES) {
        float b = bal[i] + x[i * F_NODE + 0];
        v = b * b;
    }
#pragma unroll
    for (int off = 32; off > 0; off >>= 1) v += __shfl_down(v, off, 64);
    __shared__ float wsum[4];
    int lane = threadIdx.x & 63, wid = threadIdx.x >> 6;
    if (lane == 0) wsum[wid] = v;
    __syncthreads();
    if (threadIdx.x == 0) atomicAdd(imb2, wsum[0] + wsum[1] + wsum[2] + wsum[3]);
}

__global__ void fin_kernel(const float* __restrict__ imb2, float* __restrict__ out) {
    out[0] = sqrtf(imb2[0]);
}

extern "C" void kernel_launch(void* const* d_in, const int* in_sizes, int n_in,
                              void* d_out, int out_size, void* d_ws, size_t ws_size,
                              hipStream_t stream) {
    const float* x  = (const float*)d_in[0];
    const float* ea = (const float*)d_in[1];
    const int*   ei = (const int*)d_in[2];
    const float* W1 = (const float*)d_in[3];
    const float* b1 = (const float*)d_in[4];
    const float* W2 = (const float*)d_in[5];
    const float* b2 = (const float*)d_in[6];
    const float* Wf = (const float*)d_in[7];
    const float* bf = (const float*)d_in[8];
    float* out = (float*)d_out;

    float* ws   = (float*)d_ws;
    float* deg  = ws;                         // [0, N)
    float* X    = ws + N_NODES;               // [N, 9N)   stride 8
    float* agg  = ws + 9 * (size_t)N_NODES;   // [9N, 17N) stride 8
    float* Pbuf = ws + 17 * (size_t)N_NODES;  // [17N, 18N)
    float* bal  = ws + 18 * (size_t)N_NODES;  // [18N, 19N)
    float* imb2 = ws + 19 * (size_t)N_NODES;  // [19N, 19N+1)

    const int EB = (N_EDGES + 255) / 256;     // 12500
    const int NB = (N_NODES + 255) / 256;     // 391

    // zero deg + X (incl. padding), bal + imb2
    hipMemsetAsync(deg, 0, (size_t)9 * N_NODES * sizeof(float), stream);
    hipMemsetAsync(bal, 0, ((size_t)N_NODES + 1) * sizeof(float), stream);

    deg_kernel<<<EB, 256, 0, stream>>>(ei, deg);

    for (int l = 0; l < NLAYER; l++) {
        hipMemsetAsync(agg, 0, (size_t)8 * N_NODES * sizeof(float), stream);
        edge_mlp<<<EB, 256, 0, stream>>>(ei, x, ea, X,
                                         W1 + (size_t)l * D_IN * HID,
                                         b1 + (size_t)l * HID,
                                         W2 + (size_t)l * HID * LD,
                                         b2 + (size_t)l * LD,
                                         agg);
        node_update<<<NB, 256, 0, stream>>>(agg, deg, X);
    }

    pfinal<<<NB, 256, 0, stream>>>(X, x, Wf, bf, out, Pbuf);
    flows_kernel<<<EB, 256, 0, stream>>>(ei, ea, Pbuf, out + N_NODES, bal);
    imb_kernel<<<NB, 256, 0, stream>>>(bal, x, imb2);
    fin_kernel<<<1, 1, 0, stream>>>(imb2, out + (size_t)N_NODES + N_EDGES);
}

// Round 2
// 1572.439 us; speedup vs baseline: 5.2708x; 5.2708x over previous
//
#include <hip/hip_runtime.h>
#include <math.h>

#define N_NODES 100000
#define N_EDGES 3200000
#define F_NODE 4
#define F_EDGE 4
#define LD 6
#define HID 16
#define NLAYER 8
#define D_IN 24   // 2*LD + 2*F_NODE + F_EDGE
#define EPSF 1e-6f
#define XS 8      // padded node-state stride (float4-friendly)

// ==================== preprocessing: counting sort by dst (and src CSR) ====================

__global__ __launch_bounds__(256) void count_kernel(const int* __restrict__ ei,
                                                    int* __restrict__ cnt_dst,
                                                    int* __restrict__ cnt_src) {
    int e = blockIdx.x * 256 + threadIdx.x;
    if (e >= N_EDGES) return;
    atomicAdd(&cnt_src[ei[e]], 1);
    atomicAdd(&cnt_dst[ei[N_EDGES + e]], 1);
}

__global__ __launch_bounds__(256) void deginv_kernel(const int* __restrict__ cnt_dst,
                                                     float* __restrict__ degInv) {
    int i = blockIdx.x * 256 + threadIdx.x;
    if (i < N_NODES) degInv[i] = 1.0f / fmaxf((float)cnt_dst[i], 1.0f);
}

// exclusive scan, 3-pass (256/block)
__global__ __launch_bounds__(256) void scan1(const int* __restrict__ in,
                                             int* __restrict__ out,
                                             int* __restrict__ bsum, int n) {
    __shared__ int s[256];
    int t = threadIdx.x;
    int i = blockIdx.x * 256 + t;
    int v = (i < n) ? in[i] : 0;
    s[t] = v;
    __syncthreads();
#pragma unroll
    for (int off = 1; off < 256; off <<= 1) {
        int tmp = (t >= off) ? s[t - off] : 0;
        __syncthreads();
        s[t] += tmp;
        __syncthreads();
    }
    if (i < n) out[i] = s[t] - v;
    if (t == 255) bsum[blockIdx.x] = s[255];
}

__global__ __launch_bounds__(512) void scan2(const int* __restrict__ bsum,
                                             int* __restrict__ boff, int nb) {
    __shared__ int s[512];
    int t = threadIdx.x;
    int v = (t < nb) ? bsum[t] : 0;
    s[t] = v;
    __syncthreads();
#pragma unroll
    for (int off = 1; off < 512; off <<= 1) {
        int tmp = (t >= off) ? s[t - off] : 0;
        __syncthreads();
        s[t] += tmp;
        __syncthreads();
    }
    if (t < nb) boff[t] = s[t] - v;
}

__global__ __launch_bounds__(256) void scan3(int* __restrict__ out,
                                             const int* __restrict__ boff,
                                             int n, int total) {
    int i = blockIdx.x * 256 + threadIdx.x;
    if (i < n) out[i] += boff[blockIdx.x];
    if (i == 0) out[n] = total;
}

// scatter edges into dst-sorted order (+ src CSR edge ids)
__global__ __launch_bounds__(256) void build_kernel(const int* __restrict__ ei,
                                                    const float* __restrict__ ea,
                                                    const int* __restrict__ off_dst,
                                                    const int* __restrict__ off_src,
                                                    int* __restrict__ cur_dst,
                                                    int* __restrict__ cur_src,
                                                    int* __restrict__ eid_dst,
                                                    int* __restrict__ eid_src,
                                                    int* __restrict__ srcP,
                                                    int* __restrict__ dstP,
                                                    float* __restrict__ eaP) {
    int e = blockIdx.x * 256 + threadIdx.x;
    if (e >= N_EDGES) return;
    int s = ei[e];
    int d = ei[N_EDGES + e];
    int p = off_dst[d] + atomicAdd(&cur_dst[d], 1);
    eid_dst[p] = e;
    srcP[p] = s;
    dstP[p] = d;
    reinterpret_cast<float4*>(eaP)[p] = reinterpret_cast<const float4*>(ea)[e];
    int q = off_src[s] + atomicAdd(&cur_src[s], 1);
    eid_src[q] = e;
}

// ==================== per-edge MLP on dst-sorted edges + segmented reduce ====================

__global__ __launch_bounds__(256) void edge_mlp_sorted(const int* __restrict__ srcP,
                                                       const int* __restrict__ dstP,
                                                       const float* __restrict__ eaP,
                                                       const float* __restrict__ x,
                                                       const float* __restrict__ X,
                                                       const float* __restrict__ W1,
                                                       const float* __restrict__ b1,
                                                       const float* __restrict__ W2,
                                                       const float* __restrict__ b2,
                                                       float* __restrict__ agg) {
    __shared__ float sW1[D_IN * HID];
    __shared__ float sb1[HID];
    __shared__ float sW2[HID * LD];
    __shared__ float sb2[LD];
    __shared__ float sm[256 * LD];
    __shared__ int   sd[256];
    for (int i = threadIdx.x; i < D_IN * HID; i += 256) sW1[i] = W1[i];
    for (int i = threadIdx.x; i < HID * LD; i += 256) sW2[i] = W2[i];
    if (threadIdx.x < HID) sb1[threadIdx.x] = b1[threadIdx.x];
    if (threadIdx.x < LD)  sb2[threadIdx.x] = b2[threadIdx.x];

    int t = threadIdx.x;
    int slot = blockIdx.x * 256 + t;
    bool valid = slot < N_EDGES;
    int s = 0, d = -1;
    float out[LD];
#pragma unroll
    for (int o = 0; o < LD; o++) out[o] = 0.0f;

    if (valid) {
        s = srcP[slot];
        d = dstP[slot];
    }
    __syncthreads();  // weights ready

    if (valid) {
        float m[D_IN];
        const float4* Xs = reinterpret_cast<const float4*>(X + (size_t)s * XS);
        const float4* Xd = reinterpret_cast<const float4*>(X + (size_t)d * XS);
        float4 a0 = Xs[0], a1 = Xs[1];
        float4 c0 = Xd[0], c1 = Xd[1];
        m[0] = a0.x; m[1] = a0.y; m[2] = a0.z; m[3] = a0.w; m[4] = a1.x; m[5] = a1.y;
        m[6] = c0.x; m[7] = c0.y; m[8] = c0.z; m[9] = c0.w; m[10] = c1.x; m[11] = c1.y;
        float4 ns = reinterpret_cast<const float4*>(x)[s];
        float4 nd = reinterpret_cast<const float4*>(x)[d];
        m[12] = ns.x; m[13] = ns.y; m[14] = ns.z; m[15] = ns.w;
        m[16] = nd.x; m[17] = nd.y; m[18] = nd.z; m[19] = nd.w;
        float4 ev = reinterpret_cast<const float4*>(eaP)[slot];
        m[20] = ev.x; m[21] = ev.y; m[22] = ev.z; m[23] = ev.w;

        float h[HID];
#pragma unroll
        for (int j = 0; j < HID; j++) h[j] = sb1[j];
#pragma unroll
        for (int i = 0; i < D_IN; i++) {
            float mi = m[i];
#pragma unroll
            for (int j = 0; j < HID; j++) h[j] = fmaf(mi, sW1[i * HID + j], h[j]);
        }
#pragma unroll
        for (int j = 0; j < HID; j++) h[j] = fmaxf(h[j], 0.0f);

#pragma unroll
        for (int o = 0; o < LD; o++) out[o] = sb2[o];
#pragma unroll
        for (int j = 0; j < HID; j++) {
            float hj = h[j];
#pragma unroll
            for (int o = 0; o < LD; o++) out[o] = fmaf(hj, sW2[j * LD + o], out[o]);
        }
    }

    sd[t] = d;
#pragma unroll
    for (int o = 0; o < LD; o++) sm[t * LD + o] = out[o];
    __syncthreads();

    if (valid) {
        bool head = (t == 0) || (sd[t - 1] != d);
        if (head) {
            float acc[LD];
#pragma unroll
            for (int o = 0; o < LD; o++) acc[o] = out[o];
            int u = t + 1;
            while (u < 256 && sd[u] == d) {
#pragma unroll
                for (int o = 0; o < LD; o++) acc[o] += sm[u * LD + o];
                u++;
            }
            float* a = agg + (size_t)d * XS;
#pragma unroll
            for (int o = 0; o < LD; o++) atomicAdd(&a[o], acc[o]);
        }
    }
}

// ---------------- node update: X = relu(agg * degInv) ----------------
__global__ __launch_bounds__(256) void node_update(const float* __restrict__ agg,
                                                   const float* __restrict__ degInv,
                                                   float* __restrict__ X) {
    int i = blockIdx.x * 256 + threadIdx.x;
    if (i >= N_NODES) return;
    float inv = degInv[i];
#pragma unroll
    for (int o = 0; o < LD; o++)
        X[(size_t)i * XS + o] = fmaxf(agg[(size_t)i * XS + o] * inv, 0.0f);
}

// ---------------- head ----------------
__global__ __launch_bounds__(256) void pfinal(const float* __restrict__ X,
                                              const float* __restrict__ x,
                                              const float* __restrict__ Wf,
                                              const float* __restrict__ bf,
                                              float* __restrict__ Pout,
                                              float* __restrict__ Pbuf) {
    int i = blockIdx.x * 256 + threadIdx.x;
    if (i >= N_NODES) return;
    float acc = bf[0];
#pragma unroll
    for (int o = 0; o < LD; o++) acc = fmaf(X[(size_t)i * XS + o], Wf[o], acc);
    float P = fmaxf(acc, 0.0f);
    Pout[i] = P;
    float fixed = x[i * F_NODE + 3];
    Pbuf[i] = (fixed != 0.0f) ? fixed : P;
}

// ---------------- flows (no atomics) ----------------
__global__ __launch_bounds__(256) void flows_noatomic(const int* __restrict__ ei,
                                                      const float* __restrict__ ea,
                                                      const float* __restrict__ Pbuf,
                                                      float* __restrict__ flows_out) {
    int e = blockIdx.x * 256 + threadIdx.x;
    if (e >= N_EDGES) return;
    int s = ei[e];
    int d = ei[N_EDGES + e];
    float ps = Pbuf[s], pd = Pbuf[d];
    float dp2 = ps * ps - pd * pd;
    float k = ea[(size_t)e * F_EDGE];
    float sg = (dp2 > 0.0f) ? 1.0f : ((dp2 < 0.0f) ? -1.0f : 0.0f);
    flows_out[e] = sg * sqrtf(fabsf(dp2) / k + EPSF);
}

// ---------------- balance via CSR gather + squared-sum reduce ----------------
__global__ __launch_bounds__(256) void balance_imb(const int* __restrict__ off_dst,
                                                   const int* __restrict__ eid_dst,
                                                   const int* __restrict__ off_src,
                                                   const int* __restrict__ eid_src,
                                                   const float* __restrict__ flows,
                                                   const float* __restrict__ x,
                                                   float* __restrict__ imb2) {
    int i = blockIdx.x * 256 + threadIdx.x;
    float v = 0.0f;
    if (i < N_NODES) {
        float acc = x[i * F_NODE + 0];
        int b = off_dst[i], e = off_dst[i + 1];
        for (int p = b; p < e; p++) acc += flows[eid_dst[p]];
        b = off_src[i]; e = off_src[i + 1];
        for (int p = b; p < e; p++) acc -= flows[eid_src[p]];
        v = acc * acc;
    }
#pragma unroll
    for (int off = 32; off > 0; off >>= 1) v += __shfl_down(v, off, 64);
    __shared__ float wsum[4];
    int lane = threadIdx.x & 63, wid = threadIdx.x >> 6;
    if (lane == 0) wsum[wid] = v;
    __syncthreads();
    if (threadIdx.x == 0) atomicAdd(imb2, wsum[0] + wsum[1] + wsum[2] + wsum[3]);
}

__global__ void fin_kernel(const float* __restrict__ imb2, float* __restrict__ out) {
    out[0] = sqrtf(imb2[0]);
}

// ==================== fallback path (round-0, ~7.6MB ws) ====================

__global__ __launch_bounds__(256) void deg_kernel_fb(const int* __restrict__ ei,
                                                     float* __restrict__ deg) {
    int e = blockIdx.x * 256 + threadIdx.x;
    if (e < N_EDGES) atomicAdd(&deg[ei[N_EDGES + e]], 1.0f);
}

__global__ __launch_bounds__(256) void edge_mlp_fb(const int* __restrict__ ei,
                                                   const float* __restrict__ x,
                                                   const float* __restrict__ ea,
                                                   const float* __restrict__ X,
                                                   const float* __restrict__ W1,
                                                   const float* __restrict__ b1,
                                                   const float* __restrict__ W2,
                                                   const float* __restrict__ b2,
                                                   float* __restrict__ agg) {
    __shared__ float sW1[D_IN * HID];
    __shared__ float sb1[HID];
    __shared__ float sW2[HID * LD];
    __shared__ float sb2[LD];
    for (int i = threadIdx.x; i < D_IN * HID; i += 256) sW1[i] = W1[i];
    for (int i = threadIdx.x; i < HID * LD; i += 256) sW2[i] = W2[i];
    if (threadIdx.x < HID) sb1[threadIdx.x] = b1[threadIdx.x];
    if (threadIdx.x < LD)  sb2[threadIdx.x] = b2[threadIdx.x];
    __syncthreads();

    int e = blockIdx.x * 256 + threadIdx.x;
    if (e >= N_EDGES) return;
    int s = ei[e];
    int d = ei[N_EDGES + e];

    float m[D_IN];
    const float4* Xs = reinterpret_cast<const float4*>(X + (size_t)s * XS);
    const float4* Xd = reinterpret_cast<const float4*>(X + (size_t)d * XS);
    float4 a0 = Xs[0], a1 = Xs[1];
    float4 c0 = Xd[0], c1 = Xd[1];
    m[0] = a0.x; m[1] = a0.y; m[2] = a0.z; m[3] = a0.w; m[4] = a1.x; m[5] = a1.y;
    m[6] = c0.x; m[7] = c0.y; m[8] = c0.z; m[9] = c0.w; m[10] = c1.x; m[11] = c1.y;
    float4 ns = reinterpret_cast<const float4*>(x)[s];
    float4 nd = reinterpret_cast<const float4*>(x)[d];
    m[12] = ns.x; m[13] = ns.y; m[14] = ns.z; m[15] = ns.w;
    m[16] = nd.x; m[17] = nd.y; m[18] = nd.z; m[19] = nd.w;
    float4 ev = reinterpret_cast<const float4*>(ea)[e];
    m[20] = ev.x; m[21] = ev.y; m[22] = ev.z; m[23] = ev.w;

    float h[HID];
#pragma unroll
    for (int j = 0; j < HID; j++) h[j] = sb1[j];
#pragma unroll
    for (int i = 0; i < D_IN; i++) {
        float mi = m[i];
#pragma unroll
        for (int j = 0; j < HID; j++) h[j] = fmaf(mi, sW1[i * HID + j], h[j]);
    }
#pragma unroll
    for (int j = 0; j < HID; j++) h[j] = fmaxf(h[j], 0.0f);

    float out[LD];
#pragma unroll
    for (int o = 0; o < LD; o++) out[o] = sb2[o];
#pragma unroll
    for (int j = 0; j < HID; j++) {
        float hj = h[j];
#pragma unroll
        for (int o = 0; o < LD; o++) out[o] = fmaf(hj, sW2[j * LD + o], out[o]);
    }

    float* aggd = agg + (size_t)d * XS;
#pragma unroll
    for (int o = 0; o < LD; o++) atomicAdd(&aggd[o], out[o]);
}

__global__ __launch_bounds__(256) void node_update_fb(const float* __restrict__ agg,
                                                      const float* __restrict__ deg,
                                                      float* __restrict__ X) {
    int i = blockIdx.x * 256 + threadIdx.x;
    if (i >= N_NODES) return;
    float inv = 1.0f / fmaxf(deg[i], 1.0f);
#pragma unroll
    for (int o = 0; o < LD; o++)
        X[(size_t)i * XS + o] = fmaxf(agg[(size_t)i * XS + o] * inv, 0.0f);
}

__global__ __launch_bounds__(256) void flows_kernel_fb(const int* __restrict__ ei,
                                                       const float* __restrict__ ea,
                                                       const float* __restrict__ Pbuf,
                                                       float* __restrict__ flows_out,
                                                       float* __restrict__ bal) {
    int e = blockIdx.x * 256 + threadIdx.x;
    if (e >= N_EDGES) return;
    int s = ei[e];
    int d = ei[N_EDGES + e];
    float ps = Pbuf[s], pd = Pbuf[d];
    float dp2 = ps * ps - pd * pd;
    float k = ea[(size_t)e * F_EDGE];
    float sg = (dp2 > 0.0f) ? 1.0f : ((dp2 < 0.0f) ? -1.0f : 0.0f);
    float f = sg * sqrtf(fabsf(dp2) / k + EPSF);
    flows_out[e] = f;
    atomicAdd(&bal[d], f);
    atomicAdd(&bal[s], -f);
}

__global__ __launch_bounds__(256) void imb_kernel_fb(const float* __restrict__ bal,
                                                     const float* __restrict__ x,
                                                     float* __restrict__ imb2) {
    int i = blockIdx.x * 256 + threadIdx.x;
    float v = 0.0f;
    if (i < N_NODES) {
        float b = bal[i] + x[i * F_NODE + 0];
        v = b * b;
    }
#pragma unroll
    for (int off = 32; off > 0; off >>= 1) v += __shfl_down(v, off, 64);
    __shared__ float wsum[4];
    int lane = threadIdx.x & 63, wid = threadIdx.x >> 6;
    if (lane == 0) wsum[wid] = v;
    __syncthreads();
    if (threadIdx.x == 0) atomicAdd(imb2, wsum[0] + wsum[1] + wsum[2] + wsum[3]);
}

// ==================== launch ====================

extern "C" void kernel_launch(void* const* d_in, const int* in_sizes, int n_in,
                              void* d_out, int out_size, void* d_ws, size_t ws_size,
                              hipStream_t stream) {
    const float* x  = (const float*)d_in[0];
    const float* ea = (const float*)d_in[1];
    const int*   ei = (const int*)d_in[2];
    const float* W1 = (const float*)d_in[3];
    const float* b1 = (const float*)d_in[4];
    const float* W2 = (const float*)d_in[5];
    const float* b2 = (const float*)d_in[6];
    const float* Wf = (const float*)d_in[7];
    const float* bf = (const float*)d_in[8];
    float* out = (float*)d_out;

    const size_t N = N_NODES, E = N_EDGES;
    const int EB = (N_EDGES + 255) / 256;  // 12500
    const int NB = (N_NODES + 255) / 256;  // 391

    // ---- workspace layout (elements of 4B, each array rounded to 16B) ----
    size_t o = 0;
    auto alloc = [&](size_t n) { size_t r = o; o += (n + 3) & ~(size_t)3; return r; };
    size_t o_off_dst = alloc(N + 1);
    size_t o_off_src = alloc(N + 1);
    size_t o_cnt_dst = alloc(N);
    size_t o_cnt_src = alloc(N);
    size_t o_degInv  = alloc(N);
    size_t o_bsum    = alloc(1024);
    size_t o_boff    = alloc(1024);
    size_t o_X       = alloc(8 * N);
    size_t o_agg     = alloc(8 * N);
    size_t o_Pbuf    = alloc(N);
    size_t o_imb2    = alloc(64);
    size_t o_eidd    = alloc(E);
    size_t o_eids    = alloc(E);
    size_t o_srcP    = alloc(E);
    size_t o_dstP    = alloc(E);
    size_t o_eaP     = alloc(4 * E);
    size_t need = o * 4;

    if (ws_size >= need) {
        char* wsb = (char*)d_ws;
        int*   off_dst = (int*)(wsb) + o_off_dst;
        int*   off_src = (int*)(wsb) + o_off_src;
        int*   cnt_dst = (int*)(wsb) + o_cnt_dst;
        int*   cnt_src = (int*)(wsb) + o_cnt_src;
        float* degInv  = (float*)(wsb) + o_degInv;
        int*   bsum    = (int*)(wsb) + o_bsum;
        int*   boff    = (int*)(wsb) + o_boff;
        float* X       = (float*)(wsb) + o_X;
        float* agg     = (float*)(wsb) + o_agg;
        float* Pbuf    = (float*)(wsb) + o_Pbuf;
        float* imb2    = (float*)(wsb) + o_imb2;
        int*   eid_dst = (int*)(wsb) + o_eidd;
        int*   eid_src = (int*)(wsb) + o_eids;
        int*   srcP    = (int*)(wsb) + o_srcP;
        int*   dstP    = (int*)(wsb) + o_dstP;
        float* eaP     = (float*)(wsb) + o_eaP;

        hipMemsetAsync(cnt_dst, 0, N * sizeof(int), stream);
        hipMemsetAsync(cnt_src, 0, N * sizeof(int), stream);
        hipMemsetAsync(X, 0, 8 * N * sizeof(float), stream);
        hipMemsetAsync(imb2, 0, sizeof(float), stream);

        count_kernel<<<EB, 256, 0, stream>>>(ei, cnt_dst, cnt_src);
        deginv_kernel<<<NB, 256, 0, stream>>>(cnt_dst, degInv);

        scan1<<<NB, 256, 0, stream>>>(cnt_dst, off_dst, bsum, N_NODES);
        scan2<<<1, 512, 0, stream>>>(bsum, boff, NB);
        scan3<<<NB, 256, 0, stream>>>(off_dst, boff, N_NODES, N_EDGES);
        scan1<<<NB, 256, 0, stream>>>(cnt_src, off_src, bsum, N_NODES);
        scan2<<<1, 512, 0, stream>>>(bsum, boff, NB);
        scan3<<<NB, 256, 0, stream>>>(off_src, boff, N_NODES, N_EDGES);

        hipMemsetAsync(cnt_dst, 0, N * sizeof(int), stream);  // cursors
        hipMemsetAsync(cnt_src, 0, N * sizeof(int), stream);
        build_kernel<<<EB, 256, 0, stream>>>(ei, ea, off_dst, off_src,
                                             cnt_dst, cnt_src,
                                             eid_dst, eid_src, srcP, dstP, eaP);

        for (int l = 0; l < NLAYER; l++) {
            hipMemsetAsync(agg, 0, 8 * N * sizeof(float), stream);
            edge_mlp_sorted<<<EB, 256, 0, stream>>>(srcP, dstP, eaP, x, X,
                                                    W1 + (size_t)l * D_IN * HID,
                                                    b1 + (size_t)l * HID,
                                                    W2 + (size_t)l * HID * LD,
                                                    b2 + (size_t)l * LD,
                                                    agg);
            node_update<<<NB, 256, 0, stream>>>(agg, degInv, X);
        }

        pfinal<<<NB, 256, 0, stream>>>(X, x, Wf, bf, out, Pbuf);
        flows_noatomic<<<EB, 256, 0, stream>>>(ei, ea, Pbuf, out + N);
        balance_imb<<<NB, 256, 0, stream>>>(off_dst, eid_dst, off_src, eid_src,
                                            out + N, x, imb2);
        fin_kernel<<<1, 1, 0, stream>>>(imb2, out + N + E);
    } else {
        // -------- fallback: round-0 path (19N+1 floats) --------
        float* ws   = (float*)d_ws;
        float* deg  = ws;
        float* X    = ws + N;
        float* agg  = ws + 9 * N;
        float* Pbuf = ws + 17 * N;
        float* bal  = ws + 18 * N;
        float* imb2 = ws + 19 * N;

        hipMemsetAsync(deg, 0, 9 * N * sizeof(float), stream);
        hipMemsetAsync(bal, 0, (N + 1) * sizeof(float), stream);

        deg_kernel_fb<<<EB, 256, 0, stream>>>(ei, deg);
        for (int l = 0; l < NLAYER; l++) {
            hipMemsetAsync(agg, 0, 8 * N * sizeof(float), stream);
            edge_mlp_fb<<<EB, 256, 0, stream>>>(ei, x, ea, X,
                                                W1 + (size_t)l * D_IN * HID,
                                                b1 + (size_t)l * HID,
                                                W2 + (size_t)l * HID * LD,
                                                b2 + (size_t)l * LD,
                                                agg);
            node_update_fb<<<NB, 256, 0, stream>>>(agg, deg, X);
        }
        pfinal<<<NB, 256, 0, stream>>>(X, x, Wf, bf, out, Pbuf);
        flows_kernel_fb<<<EB, 256, 0, stream>>>(ei, ea, Pbuf, out + N, bal);
        imb_kernel_fb<<<NB, 256, 0, stream>>>(bal, x, imb2);
        fin_kernel<<<1, 1, 0, stream>>>(imb2, out + N + E);
    }
}

// Round 3
// 1442.291 us; speedup vs baseline: 5.7464x; 1.0902x over previous
//
#include <hip/hip_runtime.h>
#include <math.h>

#define N_NODES 100000
#define N_EDGES 3200000
#define F_NODE 4
#define F_EDGE 4
#define LD 6
#define HID 16
#define NLAYER 8
#define D_IN 24   // 2*LD + 2*F_NODE + F_EDGE
#define EPSF 1e-6f
#define XS 8      // padded node-state stride (float4-friendly)
#define RS 8      // record stride in floats (32B): {src,dst,ea0,ea1,ea2,ea3,eorig,pad}

// ==================== preprocessing ====================

__global__ __launch_bounds__(256) void count_kernel(const int* __restrict__ ei,
                                                    int* __restrict__ cnt_dst,
                                                    int* __restrict__ cnt_src) {
    int e = blockIdx.x * 256 + threadIdx.x;
    if (e >= N_EDGES) return;
    atomicAdd(&cnt_src[ei[e]], 1);
    atomicAdd(&cnt_dst[ei[N_EDGES + e]], 1);
}

__global__ __launch_bounds__(256) void deginv_kernel(const int* __restrict__ cnt_dst,
                                                     float* __restrict__ degInv) {
    int i = blockIdx.x * 256 + threadIdx.x;
    if (i < N_NODES) degInv[i] = 1.0f / fmaxf((float)cnt_dst[i], 1.0f);
}

// exclusive scan, 3-pass
__global__ __launch_bounds__(256) void scan1(const int* __restrict__ in,
                                             int* __restrict__ out,
                                             int* __restrict__ bsum, int n) {
    __shared__ int s[256];
    int t = threadIdx.x;
    int i = blockIdx.x * 256 + t;
    int v = (i < n) ? in[i] : 0;
    s[t] = v;
    __syncthreads();
#pragma unroll
    for (int off = 1; off < 256; off <<= 1) {
        int tmp = (t >= off) ? s[t - off] : 0;
        __syncthreads();
        s[t] += tmp;
        __syncthreads();
    }
    if (i < n) out[i] = s[t] - v;
    if (t == 255) bsum[blockIdx.x] = s[255];
}

__global__ __launch_bounds__(512) void scan2(const int* __restrict__ bsum,
                                             int* __restrict__ boff, int nb) {
    __shared__ int s[512];
    int t = threadIdx.x;
    int v = (t < nb) ? bsum[t] : 0;
    s[t] = v;
    __syncthreads();
#pragma unroll
    for (int off = 1; off < 512; off <<= 1) {
        int tmp = (t >= off) ? s[t - off] : 0;
        __syncthreads();
        s[t] += tmp;
        __syncthreads();
    }
    if (t < nb) boff[t] = s[t] - v;
}

__global__ __launch_bounds__(256) void scan3(int* __restrict__ out,
                                             const int* __restrict__ boff,
                                             int n, int total) {
    int i = blockIdx.x * 256 + threadIdx.x;
    if (i < n) out[i] += boff[blockIdx.x];
    if (i == 0) out[n] = total;
}

// scatter edges into 32B records at dst-sorted positions (+ src CSR edge ids)
__global__ __launch_bounds__(256) void build2_kernel(const int* __restrict__ ei,
                                                     const float* __restrict__ ea,
                                                     const int* __restrict__ off_dst,
                                                     const int* __restrict__ off_src,
                                                     int* __restrict__ cur_dst,
                                                     int* __restrict__ cur_src,
                                                     float* __restrict__ rec,
                                                     int* __restrict__ eid_src) {
    int e = blockIdx.x * 256 + threadIdx.x;
    if (e >= N_EDGES) return;
    int s = ei[e];
    int d = ei[N_EDGES + e];
    float4 ev = reinterpret_cast<const float4*>(ea)[e];
    int p = off_dst[d] + atomicAdd(&cur_dst[d], 1);
    float4 r0 = make_float4(__int_as_float(s), __int_as_float(d), ev.x, ev.y);
    float4 r1 = make_float4(ev.z, ev.w, __int_as_float(e), 0.0f);
    float4* rp = reinterpret_cast<float4*>(rec + (size_t)p * RS);
    rp[0] = r0;
    rp[1] = r1;
    int q = off_src[s] + atomicAdd(&cur_src[s], 1);
    eid_src[q] = e;
}

// ==================== per-edge MLP + wave segmented-scan reduce ====================

__global__ __launch_bounds__(256) void edge_mlp_sorted(const float* __restrict__ rec,
                                                       const float* __restrict__ x,
                                                       const float* __restrict__ X,
                                                       const float* __restrict__ W1,
                                                       const float* __restrict__ b1,
                                                       const float* __restrict__ W2,
                                                       const float* __restrict__ b2,
                                                       float* __restrict__ agg) {
    __shared__ float sW1[D_IN * HID];
    __shared__ float sb1[HID];
    __shared__ float sW2[HID * LD];
    __shared__ float sb2[LD];
    for (int i = threadIdx.x; i < D_IN * HID; i += 256) sW1[i] = W1[i];
    for (int i = threadIdx.x; i < HID * LD; i += 256) sW2[i] = W2[i];
    if (threadIdx.x < HID) sb1[threadIdx.x] = b1[threadIdx.x];
    if (threadIdx.x < LD)  sb2[threadIdx.x] = b2[threadIdx.x];

    int t = threadIdx.x;
    int slot = blockIdx.x * 256 + t;
    bool valid = slot < N_EDGES;
    int d = -1;
    float out[LD];
#pragma unroll
    for (int o = 0; o < LD; o++) out[o] = 0.0f;

    __syncthreads();  // weights ready

    if (valid) {
        const float4* rp = reinterpret_cast<const float4*>(rec + (size_t)slot * RS);
        float4 r0 = rp[0];
        float4 r1 = rp[1];
        int s = __float_as_int(r0.x);
        d = __float_as_int(r0.y);

        float m[D_IN];
        const float4* Xs = reinterpret_cast<const float4*>(X + (size_t)s * XS);
        const float4* Xd = reinterpret_cast<const float4*>(X + (size_t)d * XS);
        float4 a0 = Xs[0], a1 = Xs[1];
        float4 c0 = Xd[0], c1 = Xd[1];
        m[0] = a0.x; m[1] = a0.y; m[2] = a0.z; m[3] = a0.w; m[4] = a1.x; m[5] = a1.y;
        m[6] = c0.x; m[7] = c0.y; m[8] = c0.z; m[9] = c0.w; m[10] = c1.x; m[11] = c1.y;
        float4 ns = reinterpret_cast<const float4*>(x)[s];
        float4 nd = reinterpret_cast<const float4*>(x)[d];
        m[12] = ns.x; m[13] = ns.y; m[14] = ns.z; m[15] = ns.w;
        m[16] = nd.x; m[17] = nd.y; m[18] = nd.z; m[19] = nd.w;
        m[20] = r0.z; m[21] = r0.w; m[22] = r1.x; m[23] = r1.y;

        float h[HID];
#pragma unroll
        for (int j = 0; j < HID; j++) h[j] = sb1[j];
#pragma unroll
        for (int i = 0; i < D_IN; i++) {
            float mi = m[i];
#pragma unroll
            for (int j = 0; j < HID; j++) h[j] = fmaf(mi, sW1[i * HID + j], h[j]);
        }
#pragma unroll
        for (int j = 0; j < HID; j++) h[j] = fmaxf(h[j], 0.0f);

#pragma unroll
        for (int o = 0; o < LD; o++) out[o] = sb2[o];
#pragma unroll
        for (int j = 0; j < HID; j++) {
            float hj = h[j];
#pragma unroll
            for (int o = 0; o < LD; o++) out[o] = fmaf(hj, sW2[j * LD + o], out[o]);
        }
    }

    // wave-level segmented inclusive scan keyed on d (dst runs are contiguous)
    int lane = t & 63;
#pragma unroll
    for (int st = 1; st < 64; st <<= 1) {
        int dup = __shfl_up(d, st, 64);
        bool same = (lane >= st) && (dup == d);
#pragma unroll
        for (int o = 0; o < LD; o++) {
            float v = __shfl_up(out[o], st, 64);
            if (same) out[o] += v;
        }
    }
    int dnext = __shfl_down(d, 1, 64);
    bool tail = (lane == 63) || (dnext != d);
    if (valid && tail) {
        float* a = agg + (size_t)d * XS;
#pragma unroll
        for (int o = 0; o < LD; o++) atomicAdd(&a[o], out[o]);
    }
}

// ---------------- node update: X = relu(agg * degInv); agg <- 0 ----------------
__global__ __launch_bounds__(256) void node_update(float* __restrict__ agg,
                                                   const float* __restrict__ degInv,
                                                   float* __restrict__ X) {
    int i = blockIdx.x * 256 + threadIdx.x;
    if (i >= N_NODES) return;
    float inv = degInv[i];
    float4* ap = reinterpret_cast<float4*>(agg + (size_t)i * XS);
    float4 a0 = ap[0], a1 = ap[1];
    float4 x0, x1;
    x0.x = fmaxf(a0.x * inv, 0.0f);
    x0.y = fmaxf(a0.y * inv, 0.0f);
    x0.z = fmaxf(a0.z * inv, 0.0f);
    x0.w = fmaxf(a0.w * inv, 0.0f);
    x1.x = fmaxf(a1.x * inv, 0.0f);
    x1.y = fmaxf(a1.y * inv, 0.0f);
    x1.z = 0.0f; x1.w = 0.0f;
    float4* xp = reinterpret_cast<float4*>(X + (size_t)i * XS);
    xp[0] = x0;
    xp[1] = x1;
    float4 z = make_float4(0.0f, 0.0f, 0.0f, 0.0f);
    ap[0] = z;
    ap[1] = z;
}

// ---------------- head ----------------
__global__ __launch_bounds__(256) void pfinal(const float* __restrict__ X,
                                              const float* __restrict__ x,
                                              const float* __restrict__ Wf,
                                              const float* __restrict__ bf,
                                              float* __restrict__ Pout,
                                              float* __restrict__ Pbuf) {
    int i = blockIdx.x * 256 + threadIdx.x;
    if (i >= N_NODES) return;
    float acc = bf[0];
#pragma unroll
    for (int o = 0; o < LD; o++) acc = fmaf(X[(size_t)i * XS + o], Wf[o], acc);
    float P = fmaxf(acc, 0.0f);
    Pout[i] = P;
    float fixed = x[i * F_NODE + 3];
    Pbuf[i] = (fixed != 0.0f) ? fixed : P;
}

// ---------------- flows (original edge order, no atomics) ----------------
__global__ __launch_bounds__(256) void flows_noatomic(const int* __restrict__ ei,
                                                      const float* __restrict__ ea,
                                                      const float* __restrict__ Pbuf,
                                                      float* __restrict__ flows_out) {
    int e = blockIdx.x * 256 + threadIdx.x;
    if (e >= N_EDGES) return;
    int s = ei[e];
    int d = ei[N_EDGES + e];
    float ps = Pbuf[s], pd = Pbuf[d];
    float dp2 = ps * ps - pd * pd;
    float k = ea[(size_t)e * F_EDGE];
    float sg = (dp2 > 0.0f) ? 1.0f : ((dp2 < 0.0f) ? -1.0f : 0.0f);
    flows_out[e] = sg * sqrtf(fabsf(dp2) / k + EPSF);
}

// ---------------- balance via CSR + records ----------------
__global__ __launch_bounds__(256) void balance_imb(const int* __restrict__ off_dst,
                                                   const float* __restrict__ rec,
                                                   const int* __restrict__ off_src,
                                                   const int* __restrict__ eid_src,
                                                   const float* __restrict__ flows,
                                                   const float* __restrict__ x,
                                                   float* __restrict__ imb2) {
    int i = blockIdx.x * 256 + threadIdx.x;
    float v = 0.0f;
    if (i < N_NODES) {
        float acc = x[i * F_NODE + 0];
        const int* recI = reinterpret_cast<const int*>(rec);
        int b = off_dst[i], e = off_dst[i + 1];
        for (int p = b; p < e; p++) acc += flows[recI[(size_t)p * RS + 6]];
        b = off_src[i]; e = off_src[i + 1];
        for (int p = b; p < e; p++) acc -= flows[eid_src[p]];
        v = acc * acc;
    }
#pragma unroll
    for (int off = 32; off > 0; off >>= 1) v += __shfl_down(v, off, 64);
    __shared__ float wsum[4];
    int lane = threadIdx.x & 63, wid = threadIdx.x >> 6;
    if (lane == 0) wsum[wid] = v;
    __syncthreads();
    if (threadIdx.x == 0) atomicAdd(imb2, wsum[0] + wsum[1] + wsum[2] + wsum[3]);
}

__global__ void fin_kernel(const float* __restrict__ imb2, float* __restrict__ out) {
    out[0] = sqrtf(imb2[0]);
}

// ==================== fallback path (round-0 style, ~7.6MB ws) ====================

__global__ __launch_bounds__(256) void deg_kernel_fb(const int* __restrict__ ei,
                                                     float* __restrict__ deg) {
    int e = blockIdx.x * 256 + threadIdx.x;
    if (e < N_EDGES) atomicAdd(&deg[ei[N_EDGES + e]], 1.0f);
}

__global__ __launch_bounds__(256) void edge_mlp_fb(const int* __restrict__ ei,
                                                   const float* __restrict__ x,
                                                   const float* __restrict__ ea,
                                                   const float* __restrict__ X,
                                                   const float* __restrict__ W1,
                                                   const float* __restrict__ b1,
                                                   const float* __restrict__ W2,
                                                   const float* __restrict__ b2,
                                                   float* __restrict__ agg) {
    __shared__ float sW1[D_IN * HID];
    __shared__ float sb1[HID];
    __shared__ float sW2[HID * LD];
    __shared__ float sb2[LD];
    for (int i = threadIdx.x; i < D_IN * HID; i += 256) sW1[i] = W1[i];
    for (int i = threadIdx.x; i < HID * LD; i += 256) sW2[i] = W2[i];
    if (threadIdx.x < HID) sb1[threadIdx.x] = b1[threadIdx.x];
    if (threadIdx.x < LD)  sb2[threadIdx.x] = b2[threadIdx.x];
    __syncthreads();

    int e = blockIdx.x * 256 + threadIdx.x;
    if (e >= N_EDGES) return;
    int s = ei[e];
    int d = ei[N_EDGES + e];

    float m[D_IN];
    const float4* Xs = reinterpret_cast<const float4*>(X + (size_t)s * XS);
    const float4* Xd = reinterpret_cast<const float4*>(X + (size_t)d * XS);
    float4 a0 = Xs[0], a1 = Xs[1];
    float4 c0 = Xd[0], c1 = Xd[1];
    m[0] = a0.x; m[1] = a0.y; m[2] = a0.z; m[3] = a0.w; m[4] = a1.x; m[5] = a1.y;
    m[6] = c0.x; m[7] = c0.y; m[8] = c0.z; m[9] = c0.w; m[10] = c1.x; m[11] = c1.y;
    float4 ns = reinterpret_cast<const float4*>(x)[s];
    float4 nd = reinterpret_cast<const float4*>(x)[d];
    m[12] = ns.x; m[13] = ns.y; m[14] = ns.z; m[15] = ns.w;
    m[16] = nd.x; m[17] = nd.y; m[18] = nd.z; m[19] = nd.w;
    float4 ev = reinterpret_cast<const float4*>(ea)[e];
    m[20] = ev.x; m[21] = ev.y; m[22] = ev.z; m[23] = ev.w;

    float h[HID];
#pragma unroll
    for (int j = 0; j < HID; j++) h[j] = sb1[j];
#pragma unroll
    for (int i = 0; i < D_IN; i++) {
        float mi = m[i];
#pragma unroll
        for (int j = 0; j < HID; j++) h[j] = fmaf(mi, sW1[i * HID + j], h[j]);
    }
#pragma unroll
    for (int j = 0; j < HID; j++) h[j] = fmaxf(h[j], 0.0f);

    float out[LD];
#pragma unroll
    for (int o = 0; o < LD; o++) out[o] = sb2[o];
#pragma unroll
    for (int j = 0; j < HID; j++) {
        float hj = h[j];
#pragma unroll
        for (int o = 0; o < LD; o++) out[o] = fmaf(hj, sW2[j * LD + o], out[o]);
    }

    float* aggd = agg + (size_t)d * XS;
#pragma unroll
    for (int o = 0; o < LD; o++) atomicAdd(&aggd[o], out[o]);
}

__global__ __launch_bounds__(256) void node_update_fb(const float* __restrict__ agg,
                                                      const float* __restrict__ deg,
                                                      float* __restrict__ X) {
    int i = blockIdx.x * 256 + threadIdx.x;
    if (i >= N_NODES) return;
    float inv = 1.0f / fmaxf(deg[i], 1.0f);
#pragma unroll
    for (int o = 0; o < LD; o++)
        X[(size_t)i * XS + o] = fmaxf(agg[(size_t)i * XS + o] * inv, 0.0f);
}

__global__ __launch_bounds__(256) void flows_kernel_fb(const int* __restrict__ ei,
                                                       const float* __restrict__ ea,
                                                       const float* __restrict__ Pbuf,
                                                       float* __restrict__ flows_out,
                                                       float* __restrict__ bal) {
    int e = blockIdx.x * 256 + threadIdx.x;
    if (e >= N_EDGES) return;
    int s = ei[e];
    int d = ei[N_EDGES + e];
    float ps = Pbuf[s], pd = Pbuf[d];
    float dp2 = ps * ps - pd * pd;
    float k = ea[(size_t)e * F_EDGE];
    float sg = (dp2 > 0.0f) ? 1.0f : ((dp2 < 0.0f) ? -1.0f : 0.0f);
    float f = sg * sqrtf(fabsf(dp2) / k + EPSF);
    flows_out[e] = f;
    atomicAdd(&bal[d], f);
    atomicAdd(&bal[s], -f);
}

__global__ __launch_bounds__(256) void imb_kernel_fb(const float* __restrict__ bal,
                                                     const float* __restrict__ x,
                                                     float* __restrict__ imb2) {
    int i = blockIdx.x * 256 + threadIdx.x;
    float v = 0.0f;
    if (i < N_NODES) {
        float b = bal[i] + x[i * F_NODE + 0];
        v = b * b;
    }
#pragma unroll
    for (int off = 32; off > 0; off >>= 1) v += __shfl_down(v, off, 64);
    __shared__ float wsum[4];
    int lane = threadIdx.x & 63, wid = threadIdx.x >> 6;
    if (lane == 0) wsum[wid] = v;
    __syncthreads();
    if (threadIdx.x == 0) atomicAdd(imb2, wsum[0] + wsum[1] + wsum[2] + wsum[3]);
}

// ==================== launch ====================

extern "C" void kernel_launch(void* const* d_in, const int* in_sizes, int n_in,
                              void* d_out, int out_size, void* d_ws, size_t ws_size,
                              hipStream_t stream) {
    const float* x  = (const float*)d_in[0];
    const float* ea = (const float*)d_in[1];
    const int*   ei = (const int*)d_in[2];
    const float* W1 = (const float*)d_in[3];
    const float* b1 = (const float*)d_in[4];
    const float* W2 = (const float*)d_in[5];
    const float* b2 = (const float*)d_in[6];
    const float* Wf = (const float*)d_in[7];
    const float* bf = (const float*)d_in[8];
    float* out = (float*)d_out;

    const size_t N = N_NODES, E = N_EDGES;
    const int EB = (N_EDGES + 255) / 256;  // 12500
    const int NB = (N_NODES + 255) / 256;  // 391

    // ---- workspace layout (4B elements, 16B-aligned chunks) ----
    size_t o = 0;
    auto alloc = [&](size_t n) { size_t r = o; o += (n + 3) & ~(size_t)3; return r; };
    size_t o_off_dst = alloc(N + 1);
    size_t o_off_src = alloc(N + 1);
    size_t o_degInv  = alloc(N);
    size_t o_bsum    = alloc(1024);
    size_t o_boff    = alloc(1024);
    size_t o_X       = alloc(8 * N);
    size_t o_agg     = alloc(8 * N);   // also holds cnt/cursor ints (2N) during build
    size_t o_Pbuf    = alloc(N);
    size_t o_imb2    = alloc(64);
    size_t o_rec     = alloc(RS * E);
    size_t o_eids    = alloc(E);
    size_t need = o * 4;

    if (ws_size >= need) {
        char* wsb = (char*)d_ws;
        int*   off_dst = (int*)(wsb) + o_off_dst;
        int*   off_src = (int*)(wsb) + o_off_src;
        float* degInv  = (float*)(wsb) + o_degInv;
        int*   bsum    = (int*)(wsb) + o_bsum;
        int*   boff    = (int*)(wsb) + o_boff;
        float* X       = (float*)(wsb) + o_X;
        float* agg     = (float*)(wsb) + o_agg;
        float* Pbuf    = (float*)(wsb) + o_Pbuf;
        float* imb2    = (float*)(wsb) + o_imb2;
        float* rec     = (float*)(wsb) + o_rec;
        int*   eid_src = (int*)(wsb) + o_eids;
        int*   cnt_dst = (int*)agg;       // overlay
        int*   cnt_src = (int*)agg + N;   // overlay

        hipMemsetAsync(cnt_dst, 0, 2 * N * sizeof(int), stream);
        hipMemsetAsync(X, 0, 8 * N * sizeof(float), stream);
        hipMemsetAsync(imb2, 0, sizeof(float), stream);

        count_kernel<<<EB, 256, 0, stream>>>(ei, cnt_dst, cnt_src);
        deginv_kernel<<<NB, 256, 0, stream>>>(cnt_dst, degInv);

        scan1<<<NB, 256, 0, stream>>>(cnt_dst, off_dst, bsum, N_NODES);
        scan2<<<1, 512, 0, stream>>>(bsum, boff, NB);
        scan3<<<NB, 256, 0, stream>>>(off_dst, boff, N_NODES, N_EDGES);
        scan1<<<NB, 256, 0, stream>>>(cnt_src, off_src, bsum, N_NODES);
        scan2<<<1, 512, 0, stream>>>(bsum, boff, NB);
        scan3<<<NB, 256, 0, stream>>>(off_src, boff, N_NODES, N_EDGES);

        hipMemsetAsync(cnt_dst, 0, 2 * N * sizeof(int), stream);  // cursors
        build2_kernel<<<EB, 256, 0, stream>>>(ei, ea, off_dst, off_src,
                                              cnt_dst, cnt_src, rec, eid_src);

        hipMemsetAsync(agg, 0, 8 * N * sizeof(float), stream);  // clear overlay

        for (int l = 0; l < NLAYER; l++) {
            edge_mlp_sorted<<<EB, 256, 0, stream>>>(rec, x, X,
                                                    W1 + (size_t)l * D_IN * HID,
                                                    b1 + (size_t)l * HID,
                                                    W2 + (size_t)l * HID * LD,
                                                    b2 + (size_t)l * LD,
                                                    agg);
            node_update<<<NB, 256, 0, stream>>>(agg, degInv, X);  // zeroes agg
        }

        pfinal<<<NB, 256, 0, stream>>>(X, x, Wf, bf, out, Pbuf);
        flows_noatomic<<<EB, 256, 0, stream>>>(ei, ea, Pbuf, out + N);
        balance_imb<<<NB, 256, 0, stream>>>(off_dst, rec, off_src, eid_src,
                                            out + N, x, imb2);
        fin_kernel<<<1, 1, 0, stream>>>(imb2, out + N + E);
    } else {
        // -------- fallback: round-0 path --------
        float* ws   = (float*)d_ws;
        float* deg  = ws;
        float* X    = ws + N;
        float* agg  = ws + 9 * N;
        float* Pbuf = ws + 17 * N;
        float* bal  = ws + 18 * N;
        float* imb2 = ws + 19 * N;

        hipMemsetAsync(deg, 0, 9 * N * sizeof(float), stream);
        hipMemsetAsync(bal, 0, (N + 1) * sizeof(float), stream);

        deg_kernel_fb<<<EB, 256, 0, stream>>>(ei, deg);
        for (int l = 0; l < NLAYER; l++) {
            hipMemsetAsync(agg, 0, 8 * N * sizeof(float), stream);
            edge_mlp_fb<<<EB, 256, 0, stream>>>(ei, x, ea, X,
                                                W1 + (size_t)l * D_IN * HID,
                                                b1 + (size_t)l * HID,
                                                W2 + (size_t)l * HID * LD,
                                                b2 + (size_t)l * LD,
                                                agg);
            node_update_fb<<<NB, 256, 0, stream>>>(agg, deg, X);
        }
        pfinal<<<NB, 256, 0, stream>>>(X, x, Wf, bf, out, Pbuf);
        flows_kernel_fb<<<EB, 256, 0, stream>>>(ei, ea, Pbuf, out + N, bal);
        imb_kernel_fb<<<NB, 256, 0, stream>>>(bal, x, imb2);
        fin_kernel<<<1, 1, 0, stream>>>(imb2, out + N + E);
    }
}

// Round 4
// 1198.066 us; speedup vs baseline: 6.9178x; 1.2038x over previous
//
#include <hip/hip_runtime.h>
#include <math.h>

#define N_NODES 100000
#define N_EDGES 3200000
#define F_NODE 4
#define F_EDGE 4
#define LD 6
#define HID 16
#define NLAYER 8
#define D_IN 24   // 2*LD + 2*F_NODE + F_EDGE
#define EPSF 1e-6f
#define XS 8      // padded node-state stride
#define RS 8      // record stride floats (32B): {src,dst,ea0,ea1,ea2,ea3,eorig,pad}

// ==================== preprocessing ====================

// counts + stable ranks (rank = atomicAdd return). ranks packed 16/16.
__global__ __launch_bounds__(256) void count_kernel(const int* __restrict__ ei,
                                                    int* __restrict__ cnt_dst,
                                                    int* __restrict__ cnt_src,
                                                    int* __restrict__ ranks) {
    int e = blockIdx.x * 256 + threadIdx.x;
    if (e >= N_EDGES) return;
    int s = ei[e];
    int d = ei[N_EDGES + e];
    int rs = atomicAdd(&cnt_src[s], 1);
    int rd = atomicAdd(&cnt_dst[d], 1);
    ranks[e] = (rd << 16) | (rs & 0xffff);
}

__global__ __launch_bounds__(256) void deginv_kernel(const int* __restrict__ cnt_dst,
                                                     float* __restrict__ degInv) {
    int i = blockIdx.x * 256 + threadIdx.x;
    if (i < N_NODES) degInv[i] = 1.0f / fmaxf((float)cnt_dst[i], 1.0f);
}

// exclusive scan, 3-pass
__global__ __launch_bounds__(256) void scan1(const int* __restrict__ in,
                                             int* __restrict__ out,
                                             int* __restrict__ bsum, int n) {
    __shared__ int s[256];
    int t = threadIdx.x;
    int i = blockIdx.x * 256 + t;
    int v = (i < n) ? in[i] : 0;
    s[t] = v;
    __syncthreads();
#pragma unroll
    for (int off = 1; off < 256; off <<= 1) {
        int tmp = (t >= off) ? s[t - off] : 0;
        __syncthreads();
        s[t] += tmp;
        __syncthreads();
    }
    if (i < n) out[i] = s[t] - v;
    if (t == 255) bsum[blockIdx.x] = s[255];
}

__global__ __launch_bounds__(512) void scan2(const int* __restrict__ bsum,
                                             int* __restrict__ boff, int nb) {
    __shared__ int s[512];
    int t = threadIdx.x;
    int v = (t < nb) ? bsum[t] : 0;
    s[t] = v;
    __syncthreads();
#pragma unroll
    for (int off = 1; off < 512; off <<= 1) {
        int tmp = (t >= off) ? s[t - off] : 0;
        __syncthreads();
        s[t] += tmp;
        __syncthreads();
    }
    if (t < nb) boff[t] = s[t] - v;
}

__global__ __launch_bounds__(256) void scan3(int* __restrict__ out,
                                             const int* __restrict__ boff,
                                             int n, int total) {
    int i = blockIdx.x * 256 + threadIdx.x;
    if (i < n) out[i] += boff[blockIdx.x];
    if (i == 0) out[n] = total;
}

// atomic-free scatter: positions derived from precomputed ranks
__global__ __launch_bounds__(256) void build3_kernel(const int* __restrict__ ei,
                                                     const float* __restrict__ ea,
                                                     const int* __restrict__ off_dst,
                                                     const int* __restrict__ off_src,
                                                     const int* __restrict__ ranks,
                                                     float* __restrict__ rec,
                                                     int* __restrict__ eid_src) {
    int e = blockIdx.x * 256 + threadIdx.x;
    if (e >= N_EDGES) return;
    int s = ei[e];
    int d = ei[N_EDGES + e];
    int rk = ranks[e];
    int rd = rk >> 16;
    int rs = rk & 0xffff;
    float4 ev = reinterpret_cast<const float4*>(ea)[e];
    int p = off_dst[d] + rd;
    float4* rp = reinterpret_cast<float4*>(rec + (size_t)p * RS);
    rp[0] = make_float4(__int_as_float(s), __int_as_float(d), ev.x, ev.y);
    rp[1] = make_float4(ev.z, ev.w, __int_as_float(e), 0.0f);
    int q = off_src[s] + rs;
    eid_src[q] = e;
}

// ==================== A/B projection tables ====================
// A[v] = X[v]@W1[rows 0..5]  + x[v]@W1[rows 12..15] + b1   (src side)
// B[v] = X[v]@W1[rows 6..11] + x[v]@W1[rows 16..19]        (dst side)

__global__ __launch_bounds__(256) void ab_init(const float* __restrict__ x,
                                               const float* __restrict__ W1,  // layer 0
                                               const float* __restrict__ b1,  // layer 0
                                               float* __restrict__ A,
                                               float* __restrict__ B) {
    __shared__ float sW[8 * HID];  // rows 12..19
    __shared__ float sb[HID];
    for (int i = threadIdx.x; i < 8 * HID; i += 256) sW[i] = W1[12 * HID + i];
    if (threadIdx.x < HID) sb[threadIdx.x] = b1[threadIdx.x];
    __syncthreads();
    int i = blockIdx.x * 256 + threadIdx.x;
    if (i >= N_NODES) return;
    float4 xv = reinterpret_cast<const float4*>(x)[i];
    float xf[4] = {xv.x, xv.y, xv.z, xv.w};
    float a[HID], b[HID];
#pragma unroll
    for (int j = 0; j < HID; j++) { a[j] = sb[j]; b[j] = 0.0f; }
#pragma unroll
    for (int r = 0; r < 4; r++) {
        float v = xf[r];
#pragma unroll
        for (int j = 0; j < HID; j++) {
            a[j] = fmaf(v, sW[r * HID + j], a[j]);
            b[j] = fmaf(v, sW[(4 + r) * HID + j], b[j]);
        }
    }
    float4* Ap = reinterpret_cast<float4*>(A + (size_t)i * HID);
    float4* Bp = reinterpret_cast<float4*>(B + (size_t)i * HID);
#pragma unroll
    for (int q = 0; q < 4; q++) {
        Ap[q] = make_float4(a[4 * q], a[4 * q + 1], a[4 * q + 2], a[4 * q + 3]);
        Bp[q] = make_float4(b[4 * q], b[4 * q + 1], b[4 * q + 2], b[4 * q + 3]);
    }
}

// ==================== per-edge MLP (projected) + wave segscan ====================

__global__ __launch_bounds__(256) void edge_mlp2(const float* __restrict__ rec,
                                                 const float* __restrict__ A,
                                                 const float* __restrict__ B,
                                                 const float* __restrict__ W1l,
                                                 const float* __restrict__ W2l,
                                                 const float* __restrict__ b2l,
                                                 float* __restrict__ agg) {
    __shared__ float sWea[4 * HID];   // rows 20..23
    __shared__ float sW2[HID * LD];
    __shared__ float sb2[LD];
    for (int i = threadIdx.x; i < 4 * HID; i += 256) sWea[i] = W1l[20 * HID + i];
    for (int i = threadIdx.x; i < HID * LD; i += 256) sW2[i] = W2l[i];
    if (threadIdx.x < LD) sb2[threadIdx.x] = b2l[threadIdx.x];

    int t = threadIdx.x;
    int slot = blockIdx.x * 256 + t;
    bool valid = slot < N_EDGES;
    int d = -1;
    float out[LD];
#pragma unroll
    for (int o = 0; o < LD; o++) out[o] = 0.0f;
    __syncthreads();

    if (valid) {
        const float4* rp = reinterpret_cast<const float4*>(rec + (size_t)slot * RS);
        float4 r0 = rp[0];
        float4 r1 = rp[1];
        int s = __float_as_int(r0.x);
        d = __float_as_int(r0.y);

        const float4* Ap = reinterpret_cast<const float4*>(A + (size_t)s * HID);
        const float4* Bp = reinterpret_cast<const float4*>(B + (size_t)d * HID);
        float h[HID];
#pragma unroll
        for (int q = 0; q < 4; q++) {
            float4 av = Ap[q];
            float4 bv = Bp[q];
            h[4 * q]     = av.x + bv.x;
            h[4 * q + 1] = av.y + bv.y;
            h[4 * q + 2] = av.z + bv.z;
            h[4 * q + 3] = av.w + bv.w;
        }
        float ef[4] = {r0.z, r0.w, r1.x, r1.y};
#pragma unroll
        for (int r = 0; r < 4; r++) {
            float v = ef[r];
#pragma unroll
            for (int j = 0; j < HID; j++) h[j] = fmaf(v, sWea[r * HID + j], h[j]);
        }
#pragma unroll
        for (int j = 0; j < HID; j++) h[j] = fmaxf(h[j], 0.0f);

#pragma unroll
        for (int o = 0; o < LD; o++) out[o] = sb2[o];
#pragma unroll
        for (int j = 0; j < HID; j++) {
            float hj = h[j];
#pragma unroll
            for (int o = 0; o < LD; o++) out[o] = fmaf(hj, sW2[j * LD + o], out[o]);
        }
    }

    // wave segmented inclusive scan keyed on d (dst-sorted runs)
    int lane = t & 63;
#pragma unroll
    for (int st = 1; st < 64; st <<= 1) {
        int dup = __shfl_up(d, st, 64);
        bool same = (lane >= st) && (dup == d);
#pragma unroll
        for (int o = 0; o < LD; o++) {
            float v = __shfl_up(out[o], st, 64);
            if (same) out[o] += v;
        }
    }
    int dnext = __shfl_down(d, 1, 64);
    bool tail = (lane == 63) || (dnext != d);
    if (valid && tail) {
        float* a = agg + (size_t)d * XS;
#pragma unroll
        for (int o = 0; o < LD; o++) atomicAdd(&a[o], out[o]);
    }
}

// ---------------- fused node update: X=relu(agg*degInv); agg<-0; A,B for next layer ----------------
template <int LAST>
__global__ __launch_bounds__(256) void node_update_fused(float* __restrict__ agg,
                                                         const float* __restrict__ degInv,
                                                         const float* __restrict__ x,
                                                         const float* __restrict__ W1n,  // next layer
                                                         const float* __restrict__ b1n,
                                                         float* __restrict__ X,
                                                         float* __restrict__ A,
                                                         float* __restrict__ B) {
    __shared__ float sW[20 * HID];  // rows 0..19 of next layer
    __shared__ float sb[HID];
    if (!LAST) {
        for (int i = threadIdx.x; i < 20 * HID; i += 256) sW[i] = W1n[i];
        if (threadIdx.x < HID) sb[threadIdx.x] = b1n[threadIdx.x];
        __syncthreads();
    }
    int i = blockIdx.x * 256 + threadIdx.x;
    if (i >= N_NODES) return;
    float inv = degInv[i];
    float4* ap = reinterpret_cast<float4*>(agg + (size_t)i * XS);
    float4 a0 = ap[0], a1 = ap[1];
    float Xv[6];
    Xv[0] = fmaxf(a0.x * inv, 0.0f);
    Xv[1] = fmaxf(a0.y * inv, 0.0f);
    Xv[2] = fmaxf(a0.z * inv, 0.0f);
    Xv[3] = fmaxf(a0.w * inv, 0.0f);
    Xv[4] = fmaxf(a1.x * inv, 0.0f);
    Xv[5] = fmaxf(a1.y * inv, 0.0f);
    float4 z = make_float4(0.0f, 0.0f, 0.0f, 0.0f);
    ap[0] = z;
    ap[1] = z;
    float4* xp = reinterpret_cast<float4*>(X + (size_t)i * XS);
    xp[0] = make_float4(Xv[0], Xv[1], Xv[2], Xv[3]);
    xp[1] = make_float4(Xv[4], Xv[5], 0.0f, 0.0f);
    if (!LAST) {
        float4 xv = reinterpret_cast<const float4*>(x)[i];
        float xf[4] = {xv.x, xv.y, xv.z, xv.w};
        float a[HID], b[HID];
#pragma unroll
        for (int j = 0; j < HID; j++) { a[j] = sb[j]; b[j] = 0.0f; }
#pragma unroll
        for (int r = 0; r < 6; r++) {
            float v = Xv[r];
#pragma unroll
            for (int j = 0; j < HID; j++) {
                a[j] = fmaf(v, sW[r * HID + j], a[j]);
                b[j] = fmaf(v, sW[(6 + r) * HID + j], b[j]);
            }
        }
#pragma unroll
        for (int r = 0; r < 4; r++) {
            float v = xf[r];
#pragma unroll
            for (int j = 0; j < HID; j++) {
                a[j] = fmaf(v, sW[(12 + r) * HID + j], a[j]);
                b[j] = fmaf(v, sW[(16 + r) * HID + j], b[j]);
            }
        }
        float4* Ap = reinterpret_cast<float4*>(A + (size_t)i * HID);
        float4* Bp = reinterpret_cast<float4*>(B + (size_t)i * HID);
#pragma unroll
        for (int q = 0; q < 4; q++) {
            Ap[q] = make_float4(a[4 * q], a[4 * q + 1], a[4 * q + 2], a[4 * q + 3]);
            Bp[q] = make_float4(b[4 * q], b[4 * q + 1], b[4 * q + 2], b[4 * q + 3]);
        }
    }
}

// ---------------- head ----------------
__global__ __launch_bounds__(256) void pfinal(const float* __restrict__ X,
                                              const float* __restrict__ x,
                                              const float* __restrict__ Wf,
                                              const float* __restrict__ bf,
                                              float* __restrict__ Pout,
                                              float* __restrict__ Pbuf) {
    int i = blockIdx.x * 256 + threadIdx.x;
    if (i >= N_NODES) return;
    float acc = bf[0];
#pragma unroll
    for (int o = 0; o < LD; o++) acc = fmaf(X[(size_t)i * XS + o], Wf[o], acc);
    float P = fmaxf(acc, 0.0f);
    Pout[i] = P;
    float fixed = x[i * F_NODE + 3];
    Pbuf[i] = (fixed != 0.0f) ? fixed : P;
}

// ---------------- flows (original order, no atomics) ----------------
__global__ __launch_bounds__(256) void flows_noatomic(const int* __restrict__ ei,
                                                      const float* __restrict__ ea,
                                                      const float* __restrict__ Pbuf,
                                                      float* __restrict__ flows_out) {
    int e = blockIdx.x * 256 + threadIdx.x;
    if (e >= N_EDGES) return;
    int s = ei[e];
    int d = ei[N_EDGES + e];
    float ps = Pbuf[s], pd = Pbuf[d];
    float dp2 = ps * ps - pd * pd;
    float k = ea[(size_t)e * F_EDGE];
    float sg = (dp2 > 0.0f) ? 1.0f : ((dp2 < 0.0f) ? -1.0f : 0.0f);
    flows_out[e] = sg * sqrtf(fabsf(dp2) / k + EPSF);
}

// ---------------- balance via CSR + records ----------------
__global__ __launch_bounds__(256) void balance_imb(const int* __restrict__ off_dst,
                                                   const float* __restrict__ rec,
                                                   const int* __restrict__ off_src,
                                                   const int* __restrict__ eid_src,
                                                   const float* __restrict__ flows,
                                                   const float* __restrict__ x,
                                                   float* __restrict__ imb2) {
    int i = blockIdx.x * 256 + threadIdx.x;
    float v = 0.0f;
    if (i < N_NODES) {
        float acc = x[i * F_NODE + 0];
        const int* recI = reinterpret_cast<const int*>(rec);
        int b = off_dst[i], e = off_dst[i + 1];
        for (int p = b; p < e; p++) acc += flows[recI[(size_t)p * RS + 6]];
        b = off_src[i]; e = off_src[i + 1];
        for (int p = b; p < e; p++) acc -= flows[eid_src[p]];
        v = acc * acc;
    }
#pragma unroll
    for (int off = 32; off > 0; off >>= 1) v += __shfl_down(v, off, 64);
    __shared__ float wsum[4];
    int lane = threadIdx.x & 63, wid = threadIdx.x >> 6;
    if (lane == 0) wsum[wid] = v;
    __syncthreads();
    if (threadIdx.x == 0) atomicAdd(imb2, wsum[0] + wsum[1] + wsum[2] + wsum[3]);
}

__global__ void fin_kernel(const float* __restrict__ imb2, float* __restrict__ out) {
    out[0] = sqrtf(imb2[0]);
}

// ==================== fallback path (round-0 style) ====================

__global__ __launch_bounds__(256) void deg_kernel_fb(const int* __restrict__ ei,
                                                     float* __restrict__ deg) {
    int e = blockIdx.x * 256 + threadIdx.x;
    if (e < N_EDGES) atomicAdd(&deg[ei[N_EDGES + e]], 1.0f);
}

__global__ __launch_bounds__(256) void edge_mlp_fb(const int* __restrict__ ei,
                                                   const float* __restrict__ x,
                                                   const float* __restrict__ ea,
                                                   const float* __restrict__ X,
                                                   const float* __restrict__ W1,
                                                   const float* __restrict__ b1,
                                                   const float* __restrict__ W2,
                                                   const float* __restrict__ b2,
                                                   float* __restrict__ agg) {
    __shared__ float sW1[D_IN * HID];
    __shared__ float sb1[HID];
    __shared__ float sW2[HID * LD];
    __shared__ float sb2[LD];
    for (int i = threadIdx.x; i < D_IN * HID; i += 256) sW1[i] = W1[i];
    for (int i = threadIdx.x; i < HID * LD; i += 256) sW2[i] = W2[i];
    if (threadIdx.x < HID) sb1[threadIdx.x] = b1[threadIdx.x];
    if (threadIdx.x < LD)  sb2[threadIdx.x] = b2[threadIdx.x];
    __syncthreads();

    int e = blockIdx.x * 256 + threadIdx.x;
    if (e >= N_EDGES) return;
    int s = ei[e];
    int d = ei[N_EDGES + e];

    float m[D_IN];
    const float4* Xs = reinterpret_cast<const float4*>(X + (size_t)s * XS);
    const float4* Xd = reinterpret_cast<const float4*>(X + (size_t)d * XS);
    float4 a0 = Xs[0], a1 = Xs[1];
    float4 c0 = Xd[0], c1 = Xd[1];
    m[0] = a0.x; m[1] = a0.y; m[2] = a0.z; m[3] = a0.w; m[4] = a1.x; m[5] = a1.y;
    m[6] = c0.x; m[7] = c0.y; m[8] = c0.z; m[9] = c0.w; m[10] = c1.x; m[11] = c1.y;
    float4 ns = reinterpret_cast<const float4*>(x)[s];
    float4 nd = reinterpret_cast<const float4*>(x)[d];
    m[12] = ns.x; m[13] = ns.y; m[14] = ns.z; m[15] = ns.w;
    m[16] = nd.x; m[17] = nd.y; m[18] = nd.z; m[19] = nd.w;
    float4 ev = reinterpret_cast<const float4*>(ea)[e];
    m[20] = ev.x; m[21] = ev.y; m[22] = ev.z; m[23] = ev.w;

    float h[HID];
#pragma unroll
    for (int j = 0; j < HID; j++) h[j] = sb1[j];
#pragma unroll
    for (int i = 0; i < D_IN; i++) {
        float mi = m[i];
#pragma unroll
        for (int j = 0; j < HID; j++) h[j] = fmaf(mi, sW1[i * HID + j], h[j]);
    }
#pragma unroll
    for (int j = 0; j < HID; j++) h[j] = fmaxf(h[j], 0.0f);

    float out[LD];
#pragma unroll
    for (int o = 0; o < LD; o++) out[o] = sb2[o];
#pragma unroll
    for (int j = 0; j < HID; j++) {
        float hj = h[j];
#pragma unroll
        for (int o = 0; o < LD; o++) out[o] = fmaf(hj, sW2[j * LD + o], out[o]);
    }

    float* aggd = agg + (size_t)d * XS;
#pragma unroll
    for (int o = 0; o < LD; o++) atomicAdd(&aggd[o], out[o]);
}

__global__ __launch_bounds__(256) void node_update_fb(const float* __restrict__ agg,
                                                      const float* __restrict__ deg,
                                                      float* __restrict__ X) {
    int i = blockIdx.x * 256 + threadIdx.x;
    if (i >= N_NODES) return;
    float inv = 1.0f / fmaxf(deg[i], 1.0f);
#pragma unroll
    for (int o = 0; o < LD; o++)
        X[(size_t)i * XS + o] = fmaxf(agg[(size_t)i * XS + o] * inv, 0.0f);
}

__global__ __launch_bounds__(256) void flows_kernel_fb(const int* __restrict__ ei,
                                                       const float* __restrict__ ea,
                                                       const float* __restrict__ Pbuf,
                                                       float* __restrict__ flows_out,
                                                       float* __restrict__ bal) {
    int e = blockIdx.x * 256 + threadIdx.x;
    if (e >= N_EDGES) return;
    int s = ei[e];
    int d = ei[N_EDGES + e];
    float ps = Pbuf[s], pd = Pbuf[d];
    float dp2 = ps * ps - pd * pd;
    float k = ea[(size_t)e * F_EDGE];
    float sg = (dp2 > 0.0f) ? 1.0f : ((dp2 < 0.0f) ? -1.0f : 0.0f);
    float f = sg * sqrtf(fabsf(dp2) / k + EPSF);
    flows_out[e] = f;
    atomicAdd(&bal[d], f);
    atomicAdd(&bal[s], -f);
}

__global__ __launch_bounds__(256) void imb_kernel_fb(const float* __restrict__ bal,
                                                     const float* __restrict__ x,
                                                     float* __restrict__ imb2) {
    int i = blockIdx.x * 256 + threadIdx.x;
    float v = 0.0f;
    if (i < N_NODES) {
        float b = bal[i] + x[i * F_NODE + 0];
        v = b * b;
    }
#pragma unroll
    for (int off = 32; off > 0; off >>= 1) v += __shfl_down(v, off, 64);
    __shared__ float wsum[4];
    int lane = threadIdx.x & 63, wid = threadIdx.x >> 6;
    if (lane == 0) wsum[wid] = v;
    __syncthreads();
    if (threadIdx.x == 0) atomicAdd(imb2, wsum[0] + wsum[1] + wsum[2] + wsum[3]);
}

// ==================== launch ====================

extern "C" void kernel_launch(void* const* d_in, const int* in_sizes, int n_in,
                              void* d_out, int out_size, void* d_ws, size_t ws_size,
                              hipStream_t stream) {
    const float* x  = (const float*)d_in[0];
    const float* ea = (const float*)d_in[1];
    const int*   ei = (const int*)d_in[2];
    const float* W1 = (const float*)d_in[3];
    const float* b1 = (const float*)d_in[4];
    const float* W2 = (const float*)d_in[5];
    const float* b2 = (const float*)d_in[6];
    const float* Wf = (const float*)d_in[7];
    const float* bf = (const float*)d_in[8];
    float* out = (float*)d_out;

    const size_t N = N_NODES, E = N_EDGES;
    const int EB = (N_EDGES + 255) / 256;  // 12500
    const int NB = (N_NODES + 255) / 256;  // 391

    // ---- workspace layout (4B elements, 16B-aligned chunks) ----
    size_t o = 0;
    auto alloc = [&](size_t n) { size_t r = o; o += (n + 3) & ~(size_t)3; return r; };
    size_t o_off_dst = alloc(N + 1);
    size_t o_off_src = alloc(N + 1);
    size_t o_degInv  = alloc(N);
    size_t o_bsum    = alloc(1024);
    size_t o_boff    = alloc(1024);
    size_t o_X       = alloc(8 * N);
    size_t o_agg     = alloc(8 * N);    // cnt ints (2N) overlay during build
    size_t o_AB      = alloc(32 * N);   // A(16N)+B(16N); ranks (E ints) overlay pre-ab_init (32N>=E)
    size_t o_Pbuf    = alloc(N);
    size_t o_imb2    = alloc(64);
    size_t o_rec     = alloc(RS * E);
    size_t o_eids    = alloc(E);
    size_t need = o * 4;

    if (ws_size >= need) {
        char* wsb = (char*)d_ws;
        int*   off_dst = (int*)(wsb) + o_off_dst;
        int*   off_src = (int*)(wsb) + o_off_src;
        float* degInv  = (float*)(wsb) + o_degInv;
        int*   bsum    = (int*)(wsb) + o_bsum;
        int*   boff    = (int*)(wsb) + o_boff;
        float* X       = (float*)(wsb) + o_X;
        float* agg     = (float*)(wsb) + o_agg;
        float* A       = (float*)(wsb) + o_AB;
        float* B       = A + 16 * N;
        float* Pbuf    = (float*)(wsb) + o_Pbuf;
        float* imb2    = (float*)(wsb) + o_imb2;
        float* rec     = (float*)(wsb) + o_rec;
        int*   eid_src = (int*)(wsb) + o_eids;
        int*   cnt_dst = (int*)agg;       // overlay
        int*   cnt_src = (int*)agg + N;   // overlay
        int*   ranks   = (int*)A;         // overlay (dead after build3)

        hipMemsetAsync(cnt_dst, 0, 2 * N * sizeof(int), stream);
        hipMemsetAsync(imb2, 0, sizeof(float), stream);

        count_kernel<<<EB, 256, 0, stream>>>(ei, cnt_dst, cnt_src, ranks);
        deginv_kernel<<<NB, 256, 0, stream>>>(cnt_dst, degInv);

        scan1<<<NB, 256, 0, stream>>>(cnt_dst, off_dst, bsum, N_NODES);
        scan2<<<1, 512, 0, stream>>>(bsum, boff, NB);
        scan3<<<NB, 256, 0, stream>>>(off_dst, boff, N_NODES, N_EDGES);
        scan1<<<NB, 256, 0, stream>>>(cnt_src, off_src, bsum, N_NODES);
        scan2<<<1, 512, 0, stream>>>(bsum, boff, NB);
        scan3<<<NB, 256, 0, stream>>>(off_src, boff, N_NODES, N_EDGES);

        build3_kernel<<<EB, 256, 0, stream>>>(ei, ea, off_dst, off_src, ranks,
                                              rec, eid_src);

        hipMemsetAsync(agg, 0, 8 * N * sizeof(float), stream);  // clear cnt overlay
        ab_init<<<NB, 256, 0, stream>>>(x, W1, b1, A, B);       // overwrites ranks overlay

        for (int l = 0; l < NLAYER; l++) {
            edge_mlp2<<<EB, 256, 0, stream>>>(rec, A, B,
                                              W1 + (size_t)l * D_IN * HID,
                                              W2 + (size_t)l * HID * LD,
                                              b2 + (size_t)l * LD,
                                              agg);
            if (l < NLAYER - 1) {
                node_update_fused<0><<<NB, 256, 0, stream>>>(agg, degInv, x,
                                                             W1 + (size_t)(l + 1) * D_IN * HID,
                                                             b1 + (size_t)(l + 1) * HID,
                                                             X, A, B);
            } else {
                node_update_fused<1><<<NB, 256, 0, stream>>>(agg, degInv, x,
                                                             W1, b1, X, A, B);
            }
        }

        pfinal<<<NB, 256, 0, stream>>>(X, x, Wf, bf, out, Pbuf);
        flows_noatomic<<<EB, 256, 0, stream>>>(ei, ea, Pbuf, out + N);
        balance_imb<<<NB, 256, 0, stream>>>(off_dst, rec, off_src, eid_src,
                                            out + N, x, imb2);
        fin_kernel<<<1, 1, 0, stream>>>(imb2, out + N + E);
    } else {
        // -------- fallback: round-0 path --------
        float* ws   = (float*)d_ws;
        float* deg  = ws;
        float* X    = ws + N;
        float* agg  = ws + 9 * N;
        float* Pbuf = ws + 17 * N;
        float* bal  = ws + 18 * N;
        float* imb2 = ws + 19 * N;

        hipMemsetAsync(deg, 0, 9 * N * sizeof(float), stream);
        hipMemsetAsync(bal, 0, (N + 1) * sizeof(float), stream);

        deg_kernel_fb<<<EB, 256, 0, stream>>>(ei, deg);
        for (int l = 0; l < NLAYER; l++) {
            hipMemsetAsync(agg, 0, 8 * N * sizeof(float), stream);
            edge_mlp_fb<<<EB, 256, 0, stream>>>(ei, x, ea, X,
                                                W1 + (size_t)l * D_IN * HID,
                                                b1 + (size_t)l * HID,
                                                W2 + (size_t)l * HID * LD,
                                                b2 + (size_t)l * LD,
                                                agg);
            node_update_fb<<<NB, 256, 0, stream>>>(agg, deg, X);
        }
        pfinal<<<NB, 256, 0, stream>>>(X, x, Wf, bf, out, Pbuf);
        flows_kernel_fb<<<EB, 256, 0, stream>>>(ei, ea, Pbuf, out + N, bal);
        imb_kernel_fb<<<NB, 256, 0, stream>>>(bal, x, imb2);
        fin_kernel<<<1, 1, 0, stream>>>(imb2, out + N + E);
    }
}